// Round 2
// 814.625 us; speedup vs baseline: 1.0220x; 1.0220x over previous
//
#include <hip/hip_runtime.h>
#include <hip/hip_bf16.h>

#define BB 2
#define SS 2048
#define DD 1024
#define HH 16
#define DEP 64

typedef short bf16x8 __attribute__((ext_vector_type(8)));
typedef float f32x4 __attribute__((ext_vector_type(4)));
typedef unsigned short us8 __attribute__((ext_vector_type(8)));

static __device__ __forceinline__ unsigned short f2bf(float f) {
    unsigned int u = __float_as_uint(f);
    u += 0x7FFFu + ((u >> 16) & 1u);   // RNE
    return (unsigned short)(u >> 16);
}

// async global->LDS, 16B per lane. LDS base is wave-uniform; HW writes
// base + lane*16.
__device__ __forceinline__ void gl_lds16(const void* g, void* l) {
    __builtin_amdgcn_global_load_lds(
        (const __attribute__((address_space(1))) unsigned int*)g,
        (__attribute__((address_space(3))) unsigned int*)l, 16, 0, 0);
}

// wave-private LDS fence: only LDS ops need to drain (lgkmcnt), NOT vmcnt.
// __threadfence_block() drains vmcnt(0) too, which serializes on completion
// of the streaming attn stores + K/V loads every iteration.
__device__ __forceinline__ void lds_fence() {
    asm volatile("s_waitcnt lgkmcnt(0)" ::: "memory");
}

// ---------------------------------------------------------------------------
// fp32 -> bf16 convert for q,k,v (z selects tensor)
// ---------------------------------------------------------------------------
__global__ __launch_bounds__(256) void conv_bf16(
    const float* __restrict__ q, const float* __restrict__ k,
    const float* __restrict__ v, unsigned short* __restrict__ qb,
    unsigned short* __restrict__ kb, unsigned short* __restrict__ vb)
{
    const int z = blockIdx.z;
    const float* src = (z == 0) ? q : (z == 1) ? k : v;
    unsigned short* dst = (z == 0) ? qb : (z == 1) ? kb : vb;
    size_t i = ((size_t)blockIdx.x * 256 + threadIdx.x) * 8;
    float4 a = *(const float4*)(src + i);
    float4 b = *(const float4*)(src + i + 4);
    us8 o;
    o[0] = f2bf(a.x); o[1] = f2bf(a.y); o[2] = f2bf(a.z); o[3] = f2bf(a.w);
    o[4] = f2bf(b.x); o[5] = f2bf(b.y); o[6] = f2bf(b.z); o[7] = f2bf(b.w);
    *(us8*)(dst + i) = o;
}

// ---------------------------------------------------------------------------
// Weight transpose+convert: Wt_z[n][k] = bf16(W_z[k][n]), 1024x1024 each
// ---------------------------------------------------------------------------
__global__ __launch_bounds__(256) void trans_w(
    const float* __restrict__ Wq, const float* __restrict__ Wk,
    const float* __restrict__ Wv, const float* __restrict__ Wo,
    unsigned short* __restrict__ Wt)
{
    __shared__ unsigned short T[64][72];
    const int z = blockIdx.z;
    const float* W = (z == 0) ? Wq : (z == 1) ? Wk : (z == 2) ? Wv : Wo;
    unsigned short* D = Wt + (size_t)z * 1024 * 1024;
    const int k0 = blockIdx.y * 64, n0 = blockIdx.x * 64;
    const int t = threadIdx.x;
    #pragma unroll
    for (int it = 0; it < 4; ++it) {
        int id = t + it * 256;       // 0..1023
        int kk = id >> 4;            // 64 rows
        int nn = (id & 15) * 4;
        float4 x = *(const float4*)(W + (size_t)(k0 + kk) * 1024 + n0 + nn);
        T[kk][nn + 0] = f2bf(x.x); T[kk][nn + 1] = f2bf(x.y);
        T[kk][nn + 2] = f2bf(x.z); T[kk][nn + 3] = f2bf(x.w);
    }
    __syncthreads();
    #pragma unroll
    for (int it = 0; it < 2; ++it) {
        int id = t + it * 256;       // 0..511
        int nn = id >> 3;            // 64
        int c8 = (id & 7) * 8;
        us8 o;
        #pragma unroll
        for (int j = 0; j < 8; ++j) o[j] = T[c8 + j][nn];
        *(us8*)(D + (size_t)(n0 + nn) * 1024 + k0 + c8) = o;
    }
}

// ---------------------------------------------------------------------------
// m97-style bf16 GEMM: A (4096 x 1024 bf16), Bt (1024 x 1024 bf16, N-major),
// 128x128 tile, BK=32, global_load_lds staging, ds_read_b128 fragments.
// MODE 0: store bf16 head-split (b,h,s,dd). MODE 1: store fp32 row-major.
// ---------------------------------------------------------------------------
template <int MODE>
__device__ __forceinline__ void gemm_bt_body(
    const unsigned short* __restrict__ A, const unsigned short* __restrict__ Bt,
    const float* __restrict__ bias, unsigned short* __restrict__ OutB,
    float* __restrict__ OutF)
{
    __shared__ unsigned short As[128 * 32];
    __shared__ unsigned short Bs[128 * 32];
    const int t = threadIdx.x;
    const int m0 = blockIdx.y * 128, n0 = blockIdx.x * 128;
    const int w = t >> 6, lane = t & 63, g = lane >> 4, li = lane & 15;
    const int wr = (w & 1) * 64, wc = (w >> 1) * 64;
    const int lrow = lane >> 2, lcol = (lane & 3) * 8;

    f32x4 acc[4][4] = {};

    for (int k0 = 0; k0 < 1024; k0 += 32) {
        #pragma unroll
        for (int i = 0; i < 2; ++i) {
            int c = w * 2 + i;                 // 16-row chunk (wave-uniform)
            int row = c * 16 + lrow;
            gl_lds16(A  + (size_t)(m0 + row) * 1024 + k0 + lcol, As + c * 512);
            gl_lds16(Bt + (size_t)(n0 + row) * 1024 + k0 + lcol, Bs + c * 512);
        }
        __syncthreads();
        bf16x8 af[4], bfr[4];
        #pragma unroll
        for (int i = 0; i < 4; ++i)
            af[i] = *(const bf16x8*)&As[(wr + i * 16 + li) * 32 + g * 8];
        #pragma unroll
        for (int j = 0; j < 4; ++j)
            bfr[j] = *(const bf16x8*)&Bs[(wc + j * 16 + li) * 32 + g * 8];
        #pragma unroll
        for (int i = 0; i < 4; ++i)
            #pragma unroll
            for (int j = 0; j < 4; ++j)
                acc[i][j] = __builtin_amdgcn_mfma_f32_16x16x32_bf16(
                    af[i], bfr[j], acc[i][j], 0, 0, 0);
        __syncthreads();
    }

    #pragma unroll
    for (int i = 0; i < 4; ++i) {
        #pragma unroll
        for (int j = 0; j < 4; ++j) {
            int n = n0 + wc + j * 16 + li;
            float bv = bias[n];
            #pragma unroll
            for (int r = 0; r < 4; ++r) {
                int m = m0 + wr + i * 16 + g * 4 + r;
                float val = acc[i][j][r] + bv;
                if (MODE == 0) {
                    int b = m >> 11, s = m & 2047, h = n >> 6, dd = n & 63;
                    OutB[(((size_t)(b * HH + h)) * SS + s) * DEP + dd] = f2bf(val);
                } else {
                    OutF[(size_t)m * 1024 + n] = val;
                }
            }
        }
    }
}

__global__ __launch_bounds__(256) void gemm_qkv(
    const unsigned short* __restrict__ qb, const unsigned short* __restrict__ kb,
    const unsigned short* __restrict__ vb, const unsigned short* __restrict__ Wt,
    const float* __restrict__ bq, const float* __restrict__ bk,
    const float* __restrict__ bv,
    unsigned short* __restrict__ Qh, unsigned short* __restrict__ Kh,
    unsigned short* __restrict__ Vh)
{
    const int z = blockIdx.z;
    const unsigned short* A = (z == 0) ? qb : (z == 1) ? kb : vb;
    const unsigned short* B = Wt + (size_t)z * 1024 * 1024;
    const float* bi = (z == 0) ? bq : (z == 1) ? bk : bv;
    unsigned short* O = (z == 0) ? Qh : (z == 1) ? Kh : Vh;
    gemm_bt_body<0>(A, B, bi, O, nullptr);
}

__global__ __launch_bounds__(256) void gemm_o(
    const unsigned short* __restrict__ A, const unsigned short* __restrict__ Wt,
    const float* __restrict__ bo, float* __restrict__ Out)
{
    gemm_bt_body<1>(A, Wt + (size_t)3 * 1024 * 1024, bo, nullptr, Out);
}

// ---------------------------------------------------------------------------
// V transpose: Vh (bh, S, 64) -> Vt (bh, 64, S), bf16
// ---------------------------------------------------------------------------
__global__ __launch_bounds__(256) void transpose_v(
    const unsigned short* __restrict__ Vh, unsigned short* __restrict__ Vt)
{
    __shared__ unsigned short T[64][65];
    const int bh = blockIdx.y;
    const int s0 = blockIdx.x * 64;
    const int t = threadIdx.x;
    #pragma unroll
    for (int c = 0; c < 2; ++c) {
        int id = t + c * 256;
        int row = id >> 3, col8 = (id & 7) * 8;
        us8 v = *(const us8*)(Vh + ((size_t)bh * SS + s0 + row) * DEP + col8);
        #pragma unroll
        for (int i = 0; i < 8; ++i) T[row][col8 + i] = v[i];
    }
    __syncthreads();
    #pragma unroll
    for (int c = 0; c < 2; ++c) {
        int id = t + c * 256;
        int d = id >> 3, col8 = (id & 7) * 8;
        us8 v;
        #pragma unroll
        for (int i = 0; i < 8; ++i) v[i] = T[col8 + i][d];
        *(us8*)(Vt + ((size_t)bh * DEP + d) * SS + s0 + col8) = v;
    }
}

// ---------------------------------------------------------------------------
// Causal attention, two-pass online softmax. One block = (bh, two 32-row
// strips: x*32.. and 2016-32x.. for causal load balance). 4 waves, each wave
// owns 16 q-rows, no cross-wave barriers. attn written as full 128-B lines
// via a per-wave LDS fp32 tile (nontemporal: write-once, keep K/V in L2).
// out_h stored bf16 (b,s,D) via LDS.
// ---------------------------------------------------------------------------
__global__ __launch_bounds__(256) void attn_kernel(
    const unsigned short* __restrict__ Qh, const unsigned short* __restrict__ Kh,
    const unsigned short* __restrict__ Vt, const float* __restrict__ mask,
    float* __restrict__ attn, unsigned short* __restrict__ out_h)
{
    __shared__ float Pf[4][16 * 36];   // per-wave 16x32 fp32 tile, stride 36
    const int bh = blockIdx.y;
    const int b = bh >> 4, h = bh & 15;
    const int t = threadIdx.x;
    const int w = t >> 6, lane = t & 63, g = lane >> 4, li = lane & 15;
    const int x = blockIdx.x;          // 0..31
    // complementary strips for causal load balance
    const int r0 = (w < 2) ? (x * 32 + w * 16) : (SS - 32 - x * 32 + (w - 2) * 16);
    const float scale = 0.125f;        // 1/sqrt(64)

    const unsigned short* Qb = Qh + (size_t)bh * SS * DEP;
    const unsigned short* Kb = Kh + (size_t)bh * SS * DEP;
    const unsigned short* Vb = Vt + (size_t)bh * DEP * SS;
    float* attn_b = attn + (size_t)bh * SS * SS;
    const float* mask_b = mask + (size_t)b * SS;

    bf16x8 aQ0 = *(const bf16x8*)(Qb + (size_t)(r0 + li) * DEP + g * 8);
    bf16x8 aQ1 = *(const bf16x8*)(Qb + (size_t)(r0 + li) * DEP + 32 + g * 8);

    float m_[4], l_[4];
    #pragma unroll
    for (int r = 0; r < 4; ++r) { m_[r] = -1e30f; l_[r] = 0.0f; }

    // ---- pass 1: exact row max + sum, 64-col chunks ----
    const int nch = ((r0 + 15) >> 6) + 1;
    for (int ch = 0; ch < nch; ++ch) {
        int cb = ch * 64;
        f32x4 c[4];
        #pragma unroll
        for (int tt = 0; tt < 4; ++tt) {
            const unsigned short* Kp = Kb + (size_t)(cb + tt * 16 + li) * DEP + g * 8;
            bf16x8 k0v = *(const bf16x8*)Kp;
            bf16x8 k1v = *(const bf16x8*)(Kp + 32);
            f32x4 z = {};
            z = __builtin_amdgcn_mfma_f32_16x16x32_bf16(aQ0, k0v, z, 0, 0, 0);
            z = __builtin_amdgcn_mfma_f32_16x16x32_bf16(aQ1, k1v, z, 0, 0, 0);
            c[tt] = z;
        }
        float mv[4];
        #pragma unroll
        for (int tt = 0; tt < 4; ++tt) mv[tt] = mask_b[cb + tt * 16 + li];
        #pragma unroll
        for (int r = 0; r < 4; ++r) {
            int row = r0 + g * 4 + r;
            float s[4];
            #pragma unroll
            for (int tt = 0; tt < 4; ++tt) {
                int col = cb + tt * 16 + li;
                float pen = fmaxf(mv[tt], (col > row) ? 1.0f : 0.0f);
                s[tt] = c[tt][r] * scale + pen * (-1e17f);
            }
            float cm = fmaxf(fmaxf(s[0], s[1]), fmaxf(s[2], s[3]));
            cm = fmaxf(cm, __shfl_xor(cm, 1));
            cm = fmaxf(cm, __shfl_xor(cm, 2));
            cm = fmaxf(cm, __shfl_xor(cm, 4));
            cm = fmaxf(cm, __shfl_xor(cm, 8));
            float mn = fmaxf(m_[r], cm);
            float ps = __expf(s[0] - mn) + __expf(s[1] - mn) +
                       __expf(s[2] - mn) + __expf(s[3] - mn);
            ps += __shfl_xor(ps, 1);
            ps += __shfl_xor(ps, 2);
            ps += __shfl_xor(ps, 4);
            ps += __shfl_xor(ps, 8);
            l_[r] = l_[r] * __expf(m_[r] - mn) + ps;
            m_[r] = mn;
        }
    }
    float rl[4];
    #pragma unroll
    for (int r = 0; r < 4; ++r) rl[r] = 1.0f / l_[r];

    // ---- pass 2: recompute, write attn (full lines), accumulate P@V ----
    f32x4 o[4] = {};
    float* Pw = Pf[w];
    const int jjc = ((r0 + 15) >> 5) + 1;
    for (int jj = 0; jj < jjc; ++jj) {
        int cb = jj * 32;
        // V fragments hoisted to iteration start: independent of the QK^T /
        // softmax chain, so their HBM/L2 latency hides under it (the memory-
        // clobber fence below would otherwise pin them after the LDS wait).
        bf16x8 vf[4];
        #pragma unroll
        for (int tt = 0; tt < 4; ++tt)
            vf[tt] = *(const bf16x8*)(Vb + (size_t)(tt * 16 + li) * SS + cb + g * 8);
        #pragma unroll
        for (int hh = 0; hh < 2; ++hh) {
            int ct = cb + hh * 16;
            const unsigned short* Kp = Kb + (size_t)(ct + li) * DEP + g * 8;
            bf16x8 k0v = *(const bf16x8*)Kp;
            bf16x8 k1v = *(const bf16x8*)(Kp + 32);
            f32x4 c = {};
            c = __builtin_amdgcn_mfma_f32_16x16x32_bf16(aQ0, k0v, c, 0, 0, 0);
            c = __builtin_amdgcn_mfma_f32_16x16x32_bf16(aQ1, k1v, c, 0, 0, 0);
            float mv = mask_b[ct + li];
            #pragma unroll
            for (int r = 0; r < 4; ++r) {
                int row = r0 + g * 4 + r;
                float pen = fmaxf(mv, (ct + li > row) ? 1.0f : 0.0f);
                float s = c[r] * scale + pen * (-1e17f);
                Pw[(g * 4 + r) * 36 + hh * 16 + li] = __expf(s - m_[r]) * rl[r];
            }
        }
        lds_fence();   // LDS-only drain: wave-private tile, lanes exchange here
        // full-128B-line attn stores: 8 lanes x float4 = one line per row.
        // Nontemporal: attn is write-once; don't evict K/V/Q from L2.
        #pragma unroll
        for (int it = 0; it < 2; ++it) {
            int rloc = it * 8 + (lane >> 3);
            int c4 = (lane & 7) * 4;
            f32x4 val = *(const f32x4*)&Pw[rloc * 36 + c4];
            __builtin_nontemporal_store(
                val, (f32x4*)(attn_b + (size_t)(r0 + rloc) * SS + cb + c4));
        }
        // A-fragment for P@V from the fp32 tile
        float pf[8];
        *(f32x4*)&pf[0] = *(const f32x4*)&Pw[li * 36 + g * 8];
        *(f32x4*)&pf[4] = *(const f32x4*)&Pw[li * 36 + g * 8 + 4];
        bf16x8 aP;
        #pragma unroll
        for (int i = 0; i < 8; ++i) aP[i] = (short)f2bf(pf[i]);
        #pragma unroll
        for (int tt = 0; tt < 4; ++tt)
            o[tt] = __builtin_amdgcn_mfma_f32_16x16x32_bf16(aP, vf[tt], o[tt], 0, 0, 0);
        lds_fence();   // WAR: reads done before next iteration overwrites Pw
    }

    // ---- zero-fill fully-masked region (guarded nontemporal stores) ----
    for (int cb = jjc * 32; cb < SS; cb += 64) {
        int col = cb + li * 4;
        if (col < SS) {
            f32x4 z4 = {0.f, 0.f, 0.f, 0.f};
            #pragma unroll
            for (int r = 0; r < 4; ++r) {
                int row = r0 + g * 4 + r;
                __builtin_nontemporal_store(
                    z4, (f32x4*)(attn_b + (size_t)row * SS + col));
            }
        }
    }

    // ---- store out_h bf16 (b,s,D) via LDS, full lines ----
    unsigned short* Ow = (unsigned short*)Pw;   // stride 72 shorts = 144 B
    #pragma unroll
    for (int tt = 0; tt < 4; ++tt)
        #pragma unroll
        for (int r = 0; r < 4; ++r)
            Ow[(g * 4 + r) * 72 + tt * 16 + li] = f2bf(o[tt][r]);
    lds_fence();
    #pragma unroll
    for (int it = 0; it < 2; ++it) {
        int rloc = it * 8 + (lane >> 3);
        int c8 = (lane & 7) * 8;
        us8 val = *(const us8*)&Ow[rloc * 72 + c8];
        *(us8*)(out_h + ((size_t)b * SS + r0 + rloc) * DD + h * DEP + c8) = val;
    }
}

// ---------------------------------------------------------------------------
extern "C" void kernel_launch(void* const* d_in, const int* in_sizes, int n_in,
                              void* d_out, int out_size, void* d_ws, size_t ws_size,
                              hipStream_t stream) {
    const float* v    = (const float*)d_in[0];
    const float* k    = (const float*)d_in[1];
    const float* q    = (const float*)d_in[2];
    const float* mask = (const float*)d_in[3];
    const float* Wq   = (const float*)d_in[4];
    const float* bq   = (const float*)d_in[5];
    const float* Wk   = (const float*)d_in[6];
    const float* bk   = (const float*)d_in[7];
    const float* Wv   = (const float*)d_in[8];
    const float* bv   = (const float*)d_in[9];
    const float* Wo   = (const float*)d_in[10];
    const float* bo   = (const float*)d_in[11];

    char* ws = (char*)d_ws;
    const size_t MB = 1 << 20;
    unsigned short* qb   = (unsigned short*)(ws + 0 * MB);   // 8 MB (later out_h)
    unsigned short* kb   = (unsigned short*)(ws + 8 * MB);   // 8 MB (later Vt)
    unsigned short* vb   = (unsigned short*)(ws + 16 * MB);  // 8 MB
    unsigned short* Qh   = (unsigned short*)(ws + 24 * MB);  // 8 MB
    unsigned short* Kh   = (unsigned short*)(ws + 32 * MB);  // 8 MB
    unsigned short* Vh   = (unsigned short*)(ws + 40 * MB);  // 8 MB
    unsigned short* Wt   = (unsigned short*)(ws + 48 * MB);  // 8 MB (4 x 2MB)
    unsigned short* out_h = qb;   // reuse: qb dead after gemm_qkv
    unsigned short* Vt    = kb;   // reuse: kb dead after gemm_qkv

    float* out_f = (float*)d_out;                 // (B,S,D) fp32
    float* attn  = out_f + (size_t)BB * SS * DD;  // (B,H,S,S) fp32

    conv_bf16<<<dim3(2048, 1, 3), 256, 0, stream>>>(q, k, v, qb, kb, vb);
    trans_w<<<dim3(16, 16, 4), 256, 0, stream>>>(Wq, Wk, Wv, Wo, Wt);
    gemm_qkv<<<dim3(8, 32, 3), 256, 0, stream>>>(qb, kb, vb, Wt, bq, bk, bv,
                                                 Qh, Kh, Vh);
    transpose_v<<<dim3(32, 32), 256, 0, stream>>>(Vh, Vt);
    attn_kernel<<<dim3(32, 32), 256, 0, stream>>>(Qh, Kh, Vt, mask, attn, out_h);
    gemm_o<<<dim3(8, 32), 256, 0, stream>>>(out_h, Wt, bo, out_f);
}

// Round 3
// 789.127 us; speedup vs baseline: 1.0550x; 1.0323x over previous
//
#include <hip/hip_runtime.h>
#include <hip/hip_bf16.h>

#define BB 2
#define SS 2048
#define DD 1024
#define HH 16
#define DEP 64

typedef short bf16x8 __attribute__((ext_vector_type(8)));
typedef float f32x4 __attribute__((ext_vector_type(4)));
typedef unsigned short us8 __attribute__((ext_vector_type(8)));

static __device__ __forceinline__ unsigned short f2bf(float f) {
    unsigned int u = __float_as_uint(f);
    u += 0x7FFFu + ((u >> 16) & 1u);   // RNE
    return (unsigned short)(u >> 16);
}

// async global->LDS, 16B per lane. LDS base is wave-uniform; HW writes
// base + lane*16.
__device__ __forceinline__ void gl_lds16(const void* g, void* l) {
    __builtin_amdgcn_global_load_lds(
        (const __attribute__((address_space(1))) unsigned int*)g,
        (__attribute__((address_space(3))) unsigned int*)l, 16, 0, 0);
}

// wave-private LDS fence: only LDS ops drain (lgkmcnt), NOT vmcnt — global
// loads/stores stay in flight across it.
__device__ __forceinline__ void lds_fence() {
    asm volatile("s_waitcnt lgkmcnt(0)" ::: "memory");
}

// ---------------------------------------------------------------------------
// fp32 -> bf16 convert for q,k,v (z selects tensor)
// ---------------------------------------------------------------------------
__global__ __launch_bounds__(256) void conv_bf16(
    const float* __restrict__ q, const float* __restrict__ k,
    const float* __restrict__ v, unsigned short* __restrict__ qb,
    unsigned short* __restrict__ kb, unsigned short* __restrict__ vb)
{
    const int z = blockIdx.z;
    const float* src = (z == 0) ? q : (z == 1) ? k : v;
    unsigned short* dst = (z == 0) ? qb : (z == 1) ? kb : vb;
    size_t i = ((size_t)blockIdx.x * 256 + threadIdx.x) * 8;
    float4 a = *(const float4*)(src + i);
    float4 b = *(const float4*)(src + i + 4);
    us8 o;
    o[0] = f2bf(a.x); o[1] = f2bf(a.y); o[2] = f2bf(a.z); o[3] = f2bf(a.w);
    o[4] = f2bf(b.x); o[5] = f2bf(b.y); o[6] = f2bf(b.z); o[7] = f2bf(b.w);
    *(us8*)(dst + i) = o;
}

// ---------------------------------------------------------------------------
// Weight transpose+convert: Wt_z[n][k] = bf16(W_z[k][n]), 1024x1024 each
// ---------------------------------------------------------------------------
__global__ __launch_bounds__(256) void trans_w(
    const float* __restrict__ Wq, const float* __restrict__ Wk,
    const float* __restrict__ Wv, const float* __restrict__ Wo,
    unsigned short* __restrict__ Wt)
{
    __shared__ unsigned short T[64][72];
    const int z = blockIdx.z;
    const float* W = (z == 0) ? Wq : (z == 1) ? Wk : (z == 2) ? Wv : Wo;
    unsigned short* D = Wt + (size_t)z * 1024 * 1024;
    const int k0 = blockIdx.y * 64, n0 = blockIdx.x * 64;
    const int t = threadIdx.x;
    #pragma unroll
    for (int it = 0; it < 4; ++it) {
        int id = t + it * 256;       // 0..1023
        int kk = id >> 4;            // 64 rows
        int nn = (id & 15) * 4;
        float4 x = *(const float4*)(W + (size_t)(k0 + kk) * 1024 + n0 + nn);
        T[kk][nn + 0] = f2bf(x.x); T[kk][nn + 1] = f2bf(x.y);
        T[kk][nn + 2] = f2bf(x.z); T[kk][nn + 3] = f2bf(x.w);
    }
    __syncthreads();
    #pragma unroll
    for (int it = 0; it < 2; ++it) {
        int id = t + it * 256;       // 0..511
        int nn = id >> 3;            // 64
        int c8 = (id & 7) * 8;
        us8 o;
        #pragma unroll
        for (int j = 0; j < 8; ++j) o[j] = T[c8 + j][nn];
        *(us8*)(D + (size_t)(n0 + nn) * 1024 + k0 + c8) = o;
    }
}

// ---------------------------------------------------------------------------
// bf16 GEMM: A (4096 x 1024 bf16), Bt (1024 x 1024 bf16, N-major),
// 128x128 tile, BK=32, DOUBLE-BUFFERED global_load_lds staging with counted
// vmcnt(4) + raw s_barrier (T3-minimum 2-phase recipe): next tile's loads
// stay in flight while the current tile computes; no full-drain stalls.
// MODE 0: store bf16 head-split (b,h,s,dd). MODE 1: store fp32 row-major.
// ---------------------------------------------------------------------------
template <int MODE>
__device__ __forceinline__ void gemm_bt_body(
    const unsigned short* __restrict__ A, const unsigned short* __restrict__ Bt,
    const float* __restrict__ bias, unsigned short* __restrict__ OutB,
    float* __restrict__ OutF)
{
    __shared__ unsigned short As[2][128 * 32];
    __shared__ unsigned short Bs[2][128 * 32];
    const int t = threadIdx.x;
    const int m0 = blockIdx.y * 128, n0 = blockIdx.x * 128;
    const int w = t >> 6, lane = t & 63, g = lane >> 4, li = lane & 15;
    const int wr = (w & 1) * 64, wc = (w >> 1) * 64;
    const int lrow = lane >> 2, lcol = (lane & 3) * 8;
    const int c0 = w * 2, c1 = w * 2 + 1;          // 16-row chunks (wave-uniform)
    const int row0 = c0 * 16 + lrow, row1 = c1 * 16 + lrow;

    f32x4 acc[4][4] = {};

    auto stage = [&](int buf, int k0) {
        gl_lds16(A  + (size_t)(m0 + row0) * 1024 + k0 + lcol, &As[buf][c0 * 512]);
        gl_lds16(A  + (size_t)(m0 + row1) * 1024 + k0 + lcol, &As[buf][c1 * 512]);
        gl_lds16(Bt + (size_t)(n0 + row0) * 1024 + k0 + lcol, &Bs[buf][c0 * 512]);
        gl_lds16(Bt + (size_t)(n0 + row1) * 1024 + k0 + lcol, &Bs[buf][c1 * 512]);
    };
    auto compute = [&](int buf) {
        bf16x8 af[4], bfr[4];
        #pragma unroll
        for (int i = 0; i < 4; ++i)
            af[i] = *(const bf16x8*)&As[buf][(wr + i * 16 + li) * 32 + g * 8];
        #pragma unroll
        for (int j = 0; j < 4; ++j)
            bfr[j] = *(const bf16x8*)&Bs[buf][(wc + j * 16 + li) * 32 + g * 8];
        #pragma unroll
        for (int i = 0; i < 4; ++i)
            #pragma unroll
            for (int j = 0; j < 4; ++j)
                acc[i][j] = __builtin_amdgcn_mfma_f32_16x16x32_bf16(
                    af[i], bfr[j], acc[i][j], 0, 0, 0);
    };

    stage(0, 0);                                   // prologue: tile 0
    for (int k0 = 0; k0 < 1024 - 32; k0 += 32) {
        const int cur = (k0 >> 5) & 1;
        stage(cur ^ 1, k0 + 32);                   // issue next tile (stays in flight)
        asm volatile("s_waitcnt vmcnt(4)" ::: "memory");  // current tile arrived
        __builtin_amdgcn_s_barrier();
        compute(cur);
        __builtin_amdgcn_s_barrier();              // all reads of buf[cur] done
    }
    asm volatile("s_waitcnt vmcnt(0)" ::: "memory");
    __builtin_amdgcn_s_barrier();
    compute(1);                                    // last tile: (1024-32)>>5 & 1 == 1

    #pragma unroll
    for (int i = 0; i < 4; ++i) {
        #pragma unroll
        for (int j = 0; j < 4; ++j) {
            int n = n0 + wc + j * 16 + li;
            float bv = bias[n];
            #pragma unroll
            for (int r = 0; r < 4; ++r) {
                int m = m0 + wr + i * 16 + g * 4 + r;
                float val = acc[i][j][r] + bv;
                if (MODE == 0) {
                    int b = m >> 11, s = m & 2047, h = n >> 6, dd = n & 63;
                    OutB[(((size_t)(b * HH + h)) * SS + s) * DEP + dd] = f2bf(val);
                } else {
                    OutF[(size_t)m * 1024 + n] = val;
                }
            }
        }
    }
}

__global__ __launch_bounds__(256) void gemm_qkv(
    const unsigned short* __restrict__ qb, const unsigned short* __restrict__ kb,
    const unsigned short* __restrict__ vb, const unsigned short* __restrict__ Wt,
    const float* __restrict__ bq, const float* __restrict__ bk,
    const float* __restrict__ bv,
    unsigned short* __restrict__ Qh, unsigned short* __restrict__ Kh,
    unsigned short* __restrict__ Vh)
{
    const int z = blockIdx.z;
    const unsigned short* A = (z == 0) ? qb : (z == 1) ? kb : vb;
    const unsigned short* B = Wt + (size_t)z * 1024 * 1024;
    const float* bi = (z == 0) ? bq : (z == 1) ? bk : bv;
    unsigned short* O = (z == 0) ? Qh : (z == 1) ? Kh : Vh;
    gemm_bt_body<0>(A, B, bi, O, nullptr);
}

__global__ __launch_bounds__(256) void gemm_o(
    const unsigned short* __restrict__ A, const unsigned short* __restrict__ Wt,
    const float* __restrict__ bo, float* __restrict__ Out)
{
    gemm_bt_body<1>(A, Wt + (size_t)3 * 1024 * 1024, bo, nullptr, Out);
}

// ---------------------------------------------------------------------------
// V transpose: Vh (bh, S, 64) -> Vt (bh, 64, S), bf16
// ---------------------------------------------------------------------------
__global__ __launch_bounds__(256) void transpose_v(
    const unsigned short* __restrict__ Vh, unsigned short* __restrict__ Vt)
{
    __shared__ unsigned short T[64][65];
    const int bh = blockIdx.y;
    const int s0 = blockIdx.x * 64;
    const int t = threadIdx.x;
    #pragma unroll
    for (int c = 0; c < 2; ++c) {
        int id = t + c * 256;
        int row = id >> 3, col8 = (id & 7) * 8;
        us8 v = *(const us8*)(Vh + ((size_t)bh * SS + s0 + row) * DEP + col8);
        #pragma unroll
        for (int i = 0; i < 8; ++i) T[row][col8 + i] = v[i];
    }
    __syncthreads();
    #pragma unroll
    for (int c = 0; c < 2; ++c) {
        int id = t + c * 256;
        int d = id >> 3, col8 = (id & 7) * 8;
        us8 v;
        #pragma unroll
        for (int i = 0; i < 8; ++i) v[i] = T[col8 + i][d];
        *(us8*)(Vt + ((size_t)bh * DEP + d) * SS + s0 + col8) = v;
    }
}

// ---------------------------------------------------------------------------
// Causal attention, two-pass online softmax. One block = (bh, two 32-row
// strips for causal load balance). 4 waves, each wave owns 16 q-rows, no
// cross-wave barriers. Pass 2 is software-pipelined: K fragments for jj+1
// are issued before the LDS fence (fences wait lgkmcnt only, so the global
// loads stay in flight across iterations); P tile is double-buffered in LDS
// so no trailing WAR fence is needed.
// ---------------------------------------------------------------------------
__global__ __launch_bounds__(256) void attn_kernel(
    const unsigned short* __restrict__ Qh, const unsigned short* __restrict__ Kh,
    const unsigned short* __restrict__ Vt, const float* __restrict__ mask,
    float* __restrict__ attn, unsigned short* __restrict__ out_h)
{
    __shared__ float Pf[4][2][16 * 36];   // per-wave double-buffered 16x32 tile
    const int bh = blockIdx.y;
    const int b = bh >> 4, h = bh & 15;
    const int t = threadIdx.x;
    const int w = t >> 6, lane = t & 63, g = lane >> 4, li = lane & 15;
    const int x = blockIdx.x;          // 0..31
    // complementary strips for causal load balance
    const int r0 = (w < 2) ? (x * 32 + w * 16) : (SS - 32 - x * 32 + (w - 2) * 16);
    const float scale = 0.125f;        // 1/sqrt(64)

    const unsigned short* Qb = Qh + (size_t)bh * SS * DEP;
    const unsigned short* Kb = Kh + (size_t)bh * SS * DEP;
    const unsigned short* Vb = Vt + (size_t)bh * DEP * SS;
    float* attn_b = attn + (size_t)bh * SS * SS;
    const float* mask_b = mask + (size_t)b * SS;

    bf16x8 aQ0 = *(const bf16x8*)(Qb + (size_t)(r0 + li) * DEP + g * 8);
    bf16x8 aQ1 = *(const bf16x8*)(Qb + (size_t)(r0 + li) * DEP + 32 + g * 8);

    float m_[4], l_[4];
    #pragma unroll
    for (int r = 0; r < 4; ++r) { m_[r] = -1e30f; l_[r] = 0.0f; }

    // ---- pass 1: exact row max + sum, 64-col chunks (no fences: compiler
    // pipelines the K loads across iterations itself) ----
    const int nch = ((r0 + 15) >> 6) + 1;
    for (int ch = 0; ch < nch; ++ch) {
        int cb = ch * 64;
        f32x4 c[4];
        #pragma unroll
        for (int tt = 0; tt < 4; ++tt) {
            const unsigned short* Kp = Kb + (size_t)(cb + tt * 16 + li) * DEP + g * 8;
            bf16x8 k0v = *(const bf16x8*)Kp;
            bf16x8 k1v = *(const bf16x8*)(Kp + 32);
            f32x4 z = {};
            z = __builtin_amdgcn_mfma_f32_16x16x32_bf16(aQ0, k0v, z, 0, 0, 0);
            z = __builtin_amdgcn_mfma_f32_16x16x32_bf16(aQ1, k1v, z, 0, 0, 0);
            c[tt] = z;
        }
        float mv[4];
        #pragma unroll
        for (int tt = 0; tt < 4; ++tt) mv[tt] = mask_b[cb + tt * 16 + li];
        #pragma unroll
        for (int r = 0; r < 4; ++r) {
            int row = r0 + g * 4 + r;
            float s[4];
            #pragma unroll
            for (int tt = 0; tt < 4; ++tt) {
                int col = cb + tt * 16 + li;
                float pen = fmaxf(mv[tt], (col > row) ? 1.0f : 0.0f);
                s[tt] = c[tt][r] * scale + pen * (-1e17f);
            }
            float cm = fmaxf(fmaxf(s[0], s[1]), fmaxf(s[2], s[3]));
            cm = fmaxf(cm, __shfl_xor(cm, 1));
            cm = fmaxf(cm, __shfl_xor(cm, 2));
            cm = fmaxf(cm, __shfl_xor(cm, 4));
            cm = fmaxf(cm, __shfl_xor(cm, 8));
            float mn = fmaxf(m_[r], cm);
            float ps = __expf(s[0] - mn) + __expf(s[1] - mn) +
                       __expf(s[2] - mn) + __expf(s[3] - mn);
            ps += __shfl_xor(ps, 1);
            ps += __shfl_xor(ps, 2);
            ps += __shfl_xor(ps, 4);
            ps += __shfl_xor(ps, 8);
            l_[r] = l_[r] * __expf(m_[r] - mn) + ps;
            m_[r] = mn;
        }
    }
    float rl[4];
    #pragma unroll
    for (int r = 0; r < 4; ++r) rl[r] = 1.0f / l_[r];

    // ---- pass 2: recompute, write attn (full lines), accumulate P@V ----
    f32x4 o[4] = {};
    const int jjc = ((r0 + 15) >> 5) + 1;

    // K fragments: [hh*2 + half] (hh = 16-col group, half = D 0..31 / 32..63)
    bf16x8 kc[4], kn[4];
    {
        const unsigned short* Kp0 = Kb + (size_t)(0 + li) * DEP + g * 8;
        const unsigned short* Kp1 = Kb + (size_t)(16 + li) * DEP + g * 8;
        kc[0] = *(const bf16x8*)Kp0; kc[1] = *(const bf16x8*)(Kp0 + 32);
        kc[2] = *(const bf16x8*)Kp1; kc[3] = *(const bf16x8*)(Kp1 + 32);
    }

    for (int jj = 0; jj < jjc; ++jj) {
        int cb = jj * 32;
        float* Pw = &Pf[w][jj & 1][0];
        // V fragments for CURRENT iter: issued early, used after the fence
        // (~QK+softmax worth of latency cover within the iteration).
        bf16x8 vf[4];
        #pragma unroll
        for (int tt = 0; tt < 4; ++tt)
            vf[tt] = *(const bf16x8*)(Vb + (size_t)(tt * 16 + li) * SS + cb + g * 8);
        // K prefetch for NEXT iter: issued before the fence, consumed next
        // iteration — full iteration of latency cover.
        if (jj + 1 < jjc) {
            const unsigned short* Kp0 = Kb + (size_t)(cb + 32 + li) * DEP + g * 8;
            const unsigned short* Kp1 = Kb + (size_t)(cb + 48 + li) * DEP + g * 8;
            kn[0] = *(const bf16x8*)Kp0; kn[1] = *(const bf16x8*)(Kp0 + 32);
            kn[2] = *(const bf16x8*)Kp1; kn[3] = *(const bf16x8*)(Kp1 + 32);
        }
        #pragma unroll
        for (int hh = 0; hh < 2; ++hh) {
            int ct = cb + hh * 16;
            f32x4 c = {};
            c = __builtin_amdgcn_mfma_f32_16x16x32_bf16(aQ0, kc[hh * 2 + 0], c, 0, 0, 0);
            c = __builtin_amdgcn_mfma_f32_16x16x32_bf16(aQ1, kc[hh * 2 + 1], c, 0, 0, 0);
            float mv = mask_b[ct + li];
            #pragma unroll
            for (int r = 0; r < 4; ++r) {
                int row = r0 + g * 4 + r;
                float pen = fmaxf(mv, (ct + li > row) ? 1.0f : 0.0f);
                float s = c[r] * scale + pen * (-1e17f);
                Pw[(g * 4 + r) * 36 + hh * 16 + li] = __expf(s - m_[r]) * rl[r];
            }
        }
        lds_fence();   // Pw writes visible to all lanes (wave-private tile)
        // full-128B-line attn stores: 8 lanes x float4 = one line per row.
        // Nontemporal: attn is write-once; don't evict K/V/Q from L2.
        #pragma unroll
        for (int it = 0; it < 2; ++it) {
            int rloc = it * 8 + (lane >> 3);
            int c4 = (lane & 7) * 4;
            f32x4 val = *(const f32x4*)&Pw[rloc * 36 + c4];
            __builtin_nontemporal_store(
                val, (f32x4*)(attn_b + (size_t)(r0 + rloc) * SS + cb + c4));
        }
        // A-fragment for P@V from the fp32 tile
        float pf[8];
        *(f32x4*)&pf[0] = *(const f32x4*)&Pw[li * 36 + g * 8];
        *(f32x4*)&pf[4] = *(const f32x4*)&Pw[li * 36 + g * 8 + 4];
        bf16x8 aP;
        #pragma unroll
        for (int i = 0; i < 8; ++i) aP[i] = (short)f2bf(pf[i]);
        #pragma unroll
        for (int tt = 0; tt < 4; ++tt)
            o[tt] = __builtin_amdgcn_mfma_f32_16x16x32_bf16(aP, vf[tt], o[tt], 0, 0, 0);
        // no trailing fence: next iteration writes the OTHER Pw buffer; this
        // buffer is reused two iterations later, past the next lds_fence().
        kc[0] = kn[0]; kc[1] = kn[1]; kc[2] = kn[2]; kc[3] = kn[3];
    }

    // ---- zero-fill fully-masked region (guarded nontemporal stores) ----
    for (int cb = jjc * 32; cb < SS; cb += 64) {
        int col = cb + li * 4;
        if (col < SS) {
            f32x4 z4 = {0.f, 0.f, 0.f, 0.f};
            #pragma unroll
            for (int r = 0; r < 4; ++r) {
                int row = r0 + g * 4 + r;
                __builtin_nontemporal_store(
                    z4, (f32x4*)(attn_b + (size_t)row * SS + col));
            }
        }
    }

    // ---- store out_h bf16 (b,s,D) via LDS, full lines ----
    unsigned short* Ow = (unsigned short*)&Pf[w][0][0];  // stride 72 shorts
    #pragma unroll
    for (int tt = 0; tt < 4; ++tt)
        #pragma unroll
        for (int r = 0; r < 4; ++r)
            Ow[(g * 4 + r) * 72 + tt * 16 + li] = f2bf(o[tt][r]);
    lds_fence();
    #pragma unroll
    for (int it = 0; it < 2; ++it) {
        int rloc = it * 8 + (lane >> 3);
        int c8 = (lane & 7) * 8;
        us8 val = *(const us8*)&Ow[rloc * 72 + c8];
        *(us8*)(out_h + ((size_t)b * SS + r0 + rloc) * DD + h * DEP + c8) = val;
    }
}

// ---------------------------------------------------------------------------
extern "C" void kernel_launch(void* const* d_in, const int* in_sizes, int n_in,
                              void* d_out, int out_size, void* d_ws, size_t ws_size,
                              hipStream_t stream) {
    const float* v    = (const float*)d_in[0];
    const float* k    = (const float*)d_in[1];
    const float* q    = (const float*)d_in[2];
    const float* mask = (const float*)d_in[3];
    const float* Wq   = (const float*)d_in[4];
    const float* bq   = (const float*)d_in[5];
    const float* Wk   = (const float*)d_in[6];
    const float* bk   = (const float*)d_in[7];
    const float* Wv   = (const float*)d_in[8];
    const float* bv   = (const float*)d_in[9];
    const float* Wo   = (const float*)d_in[10];
    const float* bo   = (const float*)d_in[11];

    char* ws = (char*)d_ws;
    const size_t MB = 1 << 20;
    unsigned short* qb   = (unsigned short*)(ws + 0 * MB);   // 8 MB (later out_h)
    unsigned short* kb   = (unsigned short*)(ws + 8 * MB);   // 8 MB (later Vt)
    unsigned short* vb   = (unsigned short*)(ws + 16 * MB);  // 8 MB
    unsigned short* Qh   = (unsigned short*)(ws + 24 * MB);  // 8 MB
    unsigned short* Kh   = (unsigned short*)(ws + 32 * MB);  // 8 MB
    unsigned short* Vh   = (unsigned short*)(ws + 40 * MB);  // 8 MB
    unsigned short* Wt   = (unsigned short*)(ws + 48 * MB);  // 8 MB (4 x 2MB)
    unsigned short* out_h = qb;   // reuse: qb dead after gemm_qkv
    unsigned short* Vt    = kb;   // reuse: kb dead after gemm_qkv

    float* out_f = (float*)d_out;                 // (B,S,D) fp32
    float* attn  = out_f + (size_t)BB * SS * DD;  // (B,H,S,S) fp32

    conv_bf16<<<dim3(2048, 1, 3), 256, 0, stream>>>(q, k, v, qb, kb, vb);
    trans_w<<<dim3(16, 16, 4), 256, 0, stream>>>(Wq, Wk, Wv, Wo, Wt);
    gemm_qkv<<<dim3(8, 32, 3), 256, 0, stream>>>(qb, kb, vb, Wt, bq, bk, bv,
                                                 Qh, Kh, Vh);
    transpose_v<<<dim3(32, 32), 256, 0, stream>>>(Vh, Vt);
    attn_kernel<<<dim3(32, 32), 256, 0, stream>>>(Qh, Kh, Vt, mask, attn, out_h);
    gemm_o<<<dim3(8, 32), 256, 0, stream>>>(out_h, Wt, bo, out_f);
}

// Round 4
// 786.677 us; speedup vs baseline: 1.0583x; 1.0031x over previous
//
#include <hip/hip_runtime.h>
#include <hip/hip_bf16.h>

#define BB 2
#define SS 2048
#define DD 1024
#define HH 16
#define DEP 64

typedef short bf16x8 __attribute__((ext_vector_type(8)));
typedef float f32x4 __attribute__((ext_vector_type(4)));
typedef unsigned short us8 __attribute__((ext_vector_type(8)));
typedef unsigned short us4 __attribute__((ext_vector_type(4)));

static __device__ __forceinline__ unsigned short f2bf(float f) {
    unsigned int u = __float_as_uint(f);
    u += 0x7FFFu + ((u >> 16) & 1u);   // RNE
    return (unsigned short)(u >> 16);
}

// async global->LDS, 16B per lane. LDS base is wave-uniform; HW writes
// base + lane*16.
__device__ __forceinline__ void gl_lds16(const void* g, void* l) {
    __builtin_amdgcn_global_load_lds(
        (const __attribute__((address_space(1))) unsigned int*)g,
        (__attribute__((address_space(3))) unsigned int*)l, 16, 0, 0);
}

// wave-private LDS fence: only LDS ops drain (lgkmcnt), NOT vmcnt — global
// loads/stores stay in flight across it.
__device__ __forceinline__ void lds_fence() {
    asm volatile("s_waitcnt lgkmcnt(0)" ::: "memory");
}

// ---------------------------------------------------------------------------
// fp32 -> bf16 convert for q,k,v (z selects tensor)
// ---------------------------------------------------------------------------
__global__ __launch_bounds__(256) void conv_bf16(
    const float* __restrict__ q, const float* __restrict__ k,
    const float* __restrict__ v, unsigned short* __restrict__ qb,
    unsigned short* __restrict__ kb, unsigned short* __restrict__ vb)
{
    const int z = blockIdx.z;
    const float* src = (z == 0) ? q : (z == 1) ? k : v;
    unsigned short* dst = (z == 0) ? qb : (z == 1) ? kb : vb;
    size_t i = ((size_t)blockIdx.x * 256 + threadIdx.x) * 8;
    float4 a = *(const float4*)(src + i);
    float4 b = *(const float4*)(src + i + 4);
    us8 o;
    o[0] = f2bf(a.x); o[1] = f2bf(a.y); o[2] = f2bf(a.z); o[3] = f2bf(a.w);
    o[4] = f2bf(b.x); o[5] = f2bf(b.y); o[6] = f2bf(b.z); o[7] = f2bf(b.w);
    *(us8*)(dst + i) = o;
}

// ---------------------------------------------------------------------------
// Weight transpose+convert: Wt_z[n][k] = bf16(W_z[k][n]), 1024x1024 each
// ---------------------------------------------------------------------------
__global__ __launch_bounds__(256) void trans_w(
    const float* __restrict__ Wq, const float* __restrict__ Wk,
    const float* __restrict__ Wv, const float* __restrict__ Wo,
    unsigned short* __restrict__ Wt)
{
    __shared__ unsigned short T[64][72];
    const int z = blockIdx.z;
    const float* W = (z == 0) ? Wq : (z == 1) ? Wk : (z == 2) ? Wv : Wo;
    unsigned short* D = Wt + (size_t)z * 1024 * 1024;
    const int k0 = blockIdx.y * 64, n0 = blockIdx.x * 64;
    const int t = threadIdx.x;
    #pragma unroll
    for (int it = 0; it < 4; ++it) {
        int id = t + it * 256;       // 0..1023
        int kk = id >> 4;            // 64 rows
        int nn = (id & 15) * 4;
        float4 x = *(const float4*)(W + (size_t)(k0 + kk) * 1024 + n0 + nn);
        T[kk][nn + 0] = f2bf(x.x); T[kk][nn + 1] = f2bf(x.y);
        T[kk][nn + 2] = f2bf(x.z); T[kk][nn + 3] = f2bf(x.w);
    }
    __syncthreads();
    #pragma unroll
    for (int it = 0; it < 2; ++it) {
        int id = t + it * 256;       // 0..511
        int nn = id >> 3;            // 64
        int c8 = (id & 7) * 8;
        us8 o;
        #pragma unroll
        for (int j = 0; j < 8; ++j) o[j] = T[c8 + j][nn];
        *(us8*)(D + (size_t)(n0 + nn) * 1024 + k0 + c8) = o;
    }
}

// ---------------------------------------------------------------------------
// bf16 GEMM: A (4096 x 1024 bf16), Bt (1024 x 1024 bf16, N-major),
// 128x128 tile, BK=32, double-buffered global_load_lds + counted vmcnt.
// MODE 0: store bf16 head-split (b,h,s,dd).
// MODE 2: store bf16 TRANSPOSED head-split Vt[(b,h,dd)][s] (fuses the old
//         transpose_v kernel; 4 consecutive s per thread -> 8B stores).
// ---------------------------------------------------------------------------
template <int MODE>
__device__ __forceinline__ void gemm_bt_body(
    const unsigned short* __restrict__ A, const unsigned short* __restrict__ Bt,
    const float* __restrict__ bias, unsigned short* __restrict__ OutB)
{
    __shared__ unsigned short As[2][128 * 32];
    __shared__ unsigned short Bs[2][128 * 32];
    const int t = threadIdx.x;
    const int m0 = blockIdx.y * 128, n0 = blockIdx.x * 128;
    const int w = t >> 6, lane = t & 63, g = lane >> 4, li = lane & 15;
    const int wr = (w & 1) * 64, wc = (w >> 1) * 64;
    const int lrow = lane >> 2, lcol = (lane & 3) * 8;
    const int c0 = w * 2, c1 = w * 2 + 1;          // 16-row chunks (wave-uniform)
    const int row0 = c0 * 16 + lrow, row1 = c1 * 16 + lrow;

    f32x4 acc[4][4] = {};

    auto stage = [&](int buf, int k0) {
        gl_lds16(A  + (size_t)(m0 + row0) * 1024 + k0 + lcol, &As[buf][c0 * 512]);
        gl_lds16(A  + (size_t)(m0 + row1) * 1024 + k0 + lcol, &As[buf][c1 * 512]);
        gl_lds16(Bt + (size_t)(n0 + row0) * 1024 + k0 + lcol, &Bs[buf][c0 * 512]);
        gl_lds16(Bt + (size_t)(n0 + row1) * 1024 + k0 + lcol, &Bs[buf][c1 * 512]);
    };
    auto compute = [&](int buf) {
        bf16x8 af[4], bfr[4];
        #pragma unroll
        for (int i = 0; i < 4; ++i)
            af[i] = *(const bf16x8*)&As[buf][(wr + i * 16 + li) * 32 + g * 8];
        #pragma unroll
        for (int j = 0; j < 4; ++j)
            bfr[j] = *(const bf16x8*)&Bs[buf][(wc + j * 16 + li) * 32 + g * 8];
        #pragma unroll
        for (int i = 0; i < 4; ++i)
            #pragma unroll
            for (int j = 0; j < 4; ++j)
                acc[i][j] = __builtin_amdgcn_mfma_f32_16x16x32_bf16(
                    af[i], bfr[j], acc[i][j], 0, 0, 0);
    };

    stage(0, 0);                                   // prologue: tile 0
    for (int k0 = 0; k0 < 1024 - 32; k0 += 32) {
        const int cur = (k0 >> 5) & 1;
        stage(cur ^ 1, k0 + 32);                   // issue next tile (in flight)
        asm volatile("s_waitcnt vmcnt(4)" ::: "memory");  // current arrived
        __builtin_amdgcn_s_barrier();
        compute(cur);
        __builtin_amdgcn_s_barrier();              // all reads of buf[cur] done
    }
    asm volatile("s_waitcnt vmcnt(0)" ::: "memory");
    __builtin_amdgcn_s_barrier();
    compute(1);                                    // last tile index 31 -> buf 1

    #pragma unroll
    for (int i = 0; i < 4; ++i) {
        #pragma unroll
        for (int j = 0; j < 4; ++j) {
            int n = n0 + wc + j * 16 + li;
            float bv = bias[n];
            if (MODE == 0) {
                #pragma unroll
                for (int r = 0; r < 4; ++r) {
                    int m = m0 + wr + i * 16 + g * 4 + r;
                    float val = acc[i][j][r] + bv;
                    int b = m >> 11, s = m & 2047, h = n >> 6, dd = n & 63;
                    OutB[(((size_t)(b * HH + h)) * SS + s) * DEP + dd] = f2bf(val);
                }
            } else {
                // MODE 2: transposed store, 4 consecutive s per thread
                int mb = m0 + wr + i * 16 + g * 4;   // multiple of 4
                int b = mb >> 11, s = mb & 2047;
                int h = n >> 6, dd = n & 63;
                us4 o4;
                #pragma unroll
                for (int r = 0; r < 4; ++r) o4[r] = f2bf(acc[i][j][r] + bv);
                *(us4*)(OutB + ((size_t)((b * HH + h) * DEP + dd)) * SS + s) = o4;
            }
        }
    }
}

__global__ __launch_bounds__(256) void gemm_qkv(
    const unsigned short* __restrict__ qb, const unsigned short* __restrict__ kb,
    const unsigned short* __restrict__ vb, const unsigned short* __restrict__ Wt,
    const float* __restrict__ bq, const float* __restrict__ bk,
    const float* __restrict__ bv,
    unsigned short* __restrict__ Qh, unsigned short* __restrict__ Kh,
    unsigned short* __restrict__ Vt)
{
    const int z = blockIdx.z;
    const unsigned short* A = (z == 0) ? qb : (z == 1) ? kb : vb;
    const unsigned short* B = Wt + (size_t)z * 1024 * 1024;
    const float* bi = (z == 0) ? bq : (z == 1) ? bk : bv;
    if (z == 2) {
        gemm_bt_body<2>(A, B, bi, Vt);     // V: direct transposed write
    } else {
        unsigned short* O = (z == 0) ? Qh : Kh;
        gemm_bt_body<0>(A, B, bi, O);
    }
}

// ---------------------------------------------------------------------------
// gemm_o: A (4096 x 1024 bf16) x Wo^T -> fp32 out. 128x64 tiles, 512 blocks
// (2 blocks/CU, 2 waves/SIMD: the dbuf pipeline has a partner wave to hide
// behind, unlike the old 128x128 / 256-block = 1-wave/SIMD version).
// ---------------------------------------------------------------------------
__global__ __launch_bounds__(256) void gemm_o(
    const unsigned short* __restrict__ A, const unsigned short* __restrict__ Wt4,
    const float* __restrict__ bo, float* __restrict__ Out)
{
    const unsigned short* Bt = Wt4 + (size_t)3 * 1024 * 1024;
    __shared__ unsigned short As[2][128 * 32];
    __shared__ unsigned short Bs[2][64 * 32];
    const int t = threadIdx.x;
    const int m0 = blockIdx.y * 128, n0 = blockIdx.x * 64;
    const int w = t >> 6, lane = t & 63, g = lane >> 4, li = lane & 15;
    const int wr = w * 32;                          // each wave: 32 rows x 64 cols
    const int lrow = lane >> 2, lcol = (lane & 3) * 8;
    const int ca0 = w * 2, ca1 = w * 2 + 1;         // A chunks (8 total)
    const int rowa0 = ca0 * 16 + lrow, rowa1 = ca1 * 16 + lrow;
    const int rowb = w * 16 + lrow;                 // B chunk w (4 total)

    f32x4 acc[2][4] = {};

    auto stage = [&](int buf, int k0) {
        gl_lds16(A  + (size_t)(m0 + rowa0) * 1024 + k0 + lcol, &As[buf][ca0 * 512]);
        gl_lds16(A  + (size_t)(m0 + rowa1) * 1024 + k0 + lcol, &As[buf][ca1 * 512]);
        gl_lds16(Bt + (size_t)(n0 + rowb) * 1024 + k0 + lcol, &Bs[buf][w * 512]);
    };
    auto compute = [&](int buf) {
        bf16x8 af[2], bfr[4];
        #pragma unroll
        for (int i = 0; i < 2; ++i)
            af[i] = *(const bf16x8*)&As[buf][(wr + i * 16 + li) * 32 + g * 8];
        #pragma unroll
        for (int j = 0; j < 4; ++j)
            bfr[j] = *(const bf16x8*)&Bs[buf][(j * 16 + li) * 32 + g * 8];
        #pragma unroll
        for (int i = 0; i < 2; ++i)
            #pragma unroll
            for (int j = 0; j < 4; ++j)
                acc[i][j] = __builtin_amdgcn_mfma_f32_16x16x32_bf16(
                    af[i], bfr[j], acc[i][j], 0, 0, 0);
    };

    stage(0, 0);
    for (int k0 = 0; k0 < 1024 - 32; k0 += 32) {
        const int cur = (k0 >> 5) & 1;
        stage(cur ^ 1, k0 + 32);
        asm volatile("s_waitcnt vmcnt(3)" ::: "memory");
        __builtin_amdgcn_s_barrier();
        compute(cur);
        __builtin_amdgcn_s_barrier();
    }
    asm volatile("s_waitcnt vmcnt(0)" ::: "memory");
    __builtin_amdgcn_s_barrier();
    compute(1);

    #pragma unroll
    for (int i = 0; i < 2; ++i) {
        #pragma unroll
        for (int j = 0; j < 4; ++j) {
            int n = n0 + j * 16 + li;
            float bv = bo[n];
            #pragma unroll
            for (int r = 0; r < 4; ++r) {
                int m = m0 + wr + i * 16 + g * 4 + r;
                Out[(size_t)m * 1024 + n] = acc[i][j][r] + bv;
            }
        }
    }
}

// ---------------------------------------------------------------------------
// Causal attention, two-pass softmax. One block = (bh, two 32-row strips for
// causal load balance). 4 waves, each wave owns 16 q-rows, no cross-wave
// barriers. Pass 1 is SHUFFLE-FREE in the loop: each lane keeps per-lane
// (m,l) partials over its own columns; one 4-step cross-lane merge at the
// end. Pass 2 software-pipelined (K prefetch across lgkm-only fences),
// P tile double-buffered, nontemporal attn stores.
// ---------------------------------------------------------------------------
__global__ __launch_bounds__(256) void attn_kernel(
    const unsigned short* __restrict__ Qh, const unsigned short* __restrict__ Kh,
    const unsigned short* __restrict__ Vt, const float* __restrict__ mask,
    float* __restrict__ attn, unsigned short* __restrict__ out_h)
{
    __shared__ float Pf[4][2][16 * 36];   // per-wave double-buffered 16x32 tile
    const int bh = blockIdx.y;
    const int b = bh >> 4, h = bh & 15;
    const int t = threadIdx.x;
    const int w = t >> 6, lane = t & 63, g = lane >> 4, li = lane & 15;
    const int x = blockIdx.x;          // 0..31
    const int r0 = (w < 2) ? (x * 32 + w * 16) : (SS - 32 - x * 32 + (w - 2) * 16);
    const float scale = 0.125f;        // 1/sqrt(64)

    const unsigned short* Qb = Qh + (size_t)bh * SS * DEP;
    const unsigned short* Kb = Kh + (size_t)bh * SS * DEP;
    const unsigned short* Vb = Vt + (size_t)bh * DEP * SS;
    float* attn_b = attn + (size_t)bh * SS * SS;
    const float* mask_b = mask + (size_t)b * SS;

    bf16x8 aQ0 = *(const bf16x8*)(Qb + (size_t)(r0 + li) * DEP + g * 8);
    bf16x8 aQ1 = *(const bf16x8*)(Qb + (size_t)(r0 + li) * DEP + 32 + g * 8);

    // per-LANE softmax partials over this lane's columns only (no shuffles
    // in the hot loop; merged across the 16 li-lanes once at the end)
    float mL[4], lL[4];
    #pragma unroll
    for (int r = 0; r < 4; ++r) { mL[r] = -1e30f; lL[r] = 0.0f; }

    // ---- pass 1: exact row max + sum, 64-col chunks ----
    const int nch = ((r0 + 15) >> 6) + 1;
    for (int ch = 0; ch < nch; ++ch) {
        int cb = ch * 64;
        f32x4 c[4];
        #pragma unroll
        for (int tt = 0; tt < 4; ++tt) {
            const unsigned short* Kp = Kb + (size_t)(cb + tt * 16 + li) * DEP + g * 8;
            bf16x8 k0v = *(const bf16x8*)Kp;
            bf16x8 k1v = *(const bf16x8*)(Kp + 32);
            f32x4 z = {};
            z = __builtin_amdgcn_mfma_f32_16x16x32_bf16(aQ0, k0v, z, 0, 0, 0);
            z = __builtin_amdgcn_mfma_f32_16x16x32_bf16(aQ1, k1v, z, 0, 0, 0);
            c[tt] = z;
        }
        float mv[4];
        #pragma unroll
        for (int tt = 0; tt < 4; ++tt) mv[tt] = mask_b[cb + tt * 16 + li];
        #pragma unroll
        for (int r = 0; r < 4; ++r) {
            int row = r0 + g * 4 + r;
            float s[4];
            #pragma unroll
            for (int tt = 0; tt < 4; ++tt) {
                int col = cb + tt * 16 + li;
                float pen = fmaxf(mv[tt], (col > row) ? 1.0f : 0.0f);
                s[tt] = c[tt][r] * scale + pen * (-1e17f);
            }
            float cm = fmaxf(fmaxf(s[0], s[1]), fmaxf(s[2], s[3]));
            float mn = fmaxf(mL[r], cm);
            lL[r] = lL[r] * __expf(mL[r] - mn) +
                    __expf(s[0] - mn) + __expf(s[1] - mn) +
                    __expf(s[2] - mn) + __expf(s[3] - mn);
            mL[r] = mn;
        }
    }
    // ---- end-of-pass-1 merge across the 16 li lanes (once per wave) ----
    float m_[4], rl[4];
    #pragma unroll
    for (int r = 0; r < 4; ++r) {
        float m = mL[r], l = lL[r];
        #pragma unroll
        for (int d = 1; d < 16; d <<= 1) {
            float mo = __shfl_xor(m, d);
            float lo = __shfl_xor(l, d);
            float mn = fmaxf(m, mo);
            l = l * __expf(m - mn) + lo * __expf(mo - mn);
            m = mn;
        }
        m_[r] = m;
        rl[r] = 1.0f / l;
    }

    // ---- pass 2: recompute, write attn (full lines), accumulate P@V ----
    f32x4 o[4] = {};
    const int jjc = ((r0 + 15) >> 5) + 1;

    bf16x8 kc[4], kn[4];
    {
        const unsigned short* Kp0 = Kb + (size_t)(0 + li) * DEP + g * 8;
        const unsigned short* Kp1 = Kb + (size_t)(16 + li) * DEP + g * 8;
        kc[0] = *(const bf16x8*)Kp0; kc[1] = *(const bf16x8*)(Kp0 + 32);
        kc[2] = *(const bf16x8*)Kp1; kc[3] = *(const bf16x8*)(Kp1 + 32);
    }

    for (int jj = 0; jj < jjc; ++jj) {
        int cb = jj * 32;
        float* Pw = &Pf[w][jj & 1][0];
        bf16x8 vf[4];
        #pragma unroll
        for (int tt = 0; tt < 4; ++tt)
            vf[tt] = *(const bf16x8*)(Vb + (size_t)(tt * 16 + li) * SS + cb + g * 8);
        if (jj + 1 < jjc) {
            const unsigned short* Kp0 = Kb + (size_t)(cb + 32 + li) * DEP + g * 8;
            const unsigned short* Kp1 = Kb + (size_t)(cb + 48 + li) * DEP + g * 8;
            kn[0] = *(const bf16x8*)Kp0; kn[1] = *(const bf16x8*)(Kp0 + 32);
            kn[2] = *(const bf16x8*)Kp1; kn[3] = *(const bf16x8*)(Kp1 + 32);
        }
        #pragma unroll
        for (int hh = 0; hh < 2; ++hh) {
            int ct = cb + hh * 16;
            f32x4 c = {};
            c = __builtin_amdgcn_mfma_f32_16x16x32_bf16(aQ0, kc[hh * 2 + 0], c, 0, 0, 0);
            c = __builtin_amdgcn_mfma_f32_16x16x32_bf16(aQ1, kc[hh * 2 + 1], c, 0, 0, 0);
            float mv = mask_b[ct + li];
            #pragma unroll
            for (int r = 0; r < 4; ++r) {
                int row = r0 + g * 4 + r;
                float pen = fmaxf(mv, (ct + li > row) ? 1.0f : 0.0f);
                float s = c[r] * scale + pen * (-1e17f);
                Pw[(g * 4 + r) * 36 + hh * 16 + li] = __expf(s - m_[r]) * rl[r];
            }
        }
        lds_fence();   // Pw writes visible within the wave
        #pragma unroll
        for (int it = 0; it < 2; ++it) {
            int rloc = it * 8 + (lane >> 3);
            int c4 = (lane & 7) * 4;
            f32x4 val = *(const f32x4*)&Pw[rloc * 36 + c4];
            __builtin_nontemporal_store(
                val, (f32x4*)(attn_b + (size_t)(r0 + rloc) * SS + cb + c4));
        }
        float pf[8];
        *(f32x4*)&pf[0] = *(const f32x4*)&Pw[li * 36 + g * 8];
        *(f32x4*)&pf[4] = *(const f32x4*)&Pw[li * 36 + g * 8 + 4];
        bf16x8 aP;
        #pragma unroll
        for (int i = 0; i < 8; ++i) aP[i] = (short)f2bf(pf[i]);
        #pragma unroll
        for (int tt = 0; tt < 4; ++tt)
            o[tt] = __builtin_amdgcn_mfma_f32_16x16x32_bf16(aP, vf[tt], o[tt], 0, 0, 0);
        kc[0] = kn[0]; kc[1] = kn[1]; kc[2] = kn[2]; kc[3] = kn[3];
    }

    // ---- zero-fill fully-masked region ----
    for (int cb = jjc * 32; cb < SS; cb += 64) {
        int col = cb + li * 4;
        if (col < SS) {
            f32x4 z4 = {0.f, 0.f, 0.f, 0.f};
            #pragma unroll
            for (int r = 0; r < 4; ++r) {
                int row = r0 + g * 4 + r;
                __builtin_nontemporal_store(
                    z4, (f32x4*)(attn_b + (size_t)row * SS + col));
            }
        }
    }

    // ---- store out_h bf16 (b,s,D) via LDS, full lines ----
    unsigned short* Ow = (unsigned short*)&Pf[w][0][0];  // stride 72 shorts
    #pragma unroll
    for (int tt = 0; tt < 4; ++tt)
        #pragma unroll
        for (int r = 0; r < 4; ++r)
            Ow[(g * 4 + r) * 72 + tt * 16 + li] = f2bf(o[tt][r]);
    lds_fence();
    #pragma unroll
    for (int it = 0; it < 2; ++it) {
        int rloc = it * 8 + (lane >> 3);
        int c8 = (lane & 7) * 8;
        us8 val = *(const us8*)&Ow[rloc * 72 + c8];
        *(us8*)(out_h + ((size_t)b * SS + r0 + rloc) * DD + h * DEP + c8) = val;
    }
}

// ---------------------------------------------------------------------------
extern "C" void kernel_launch(void* const* d_in, const int* in_sizes, int n_in,
                              void* d_out, int out_size, void* d_ws, size_t ws_size,
                              hipStream_t stream) {
    const float* v    = (const float*)d_in[0];
    const float* k    = (const float*)d_in[1];
    const float* q    = (const float*)d_in[2];
    const float* mask = (const float*)d_in[3];
    const float* Wq   = (const float*)d_in[4];
    const float* bq   = (const float*)d_in[5];
    const float* Wk   = (const float*)d_in[6];
    const float* bk   = (const float*)d_in[7];
    const float* Wv   = (const float*)d_in[8];
    const float* bv   = (const float*)d_in[9];
    const float* Wo   = (const float*)d_in[10];
    const float* bo   = (const float*)d_in[11];

    char* ws = (char*)d_ws;
    const size_t MB = 1 << 20;
    unsigned short* qb   = (unsigned short*)(ws + 0 * MB);   // 8 MB (later out_h)
    unsigned short* kb   = (unsigned short*)(ws + 8 * MB);   // 8 MB
    unsigned short* vb   = (unsigned short*)(ws + 16 * MB);  // 8 MB
    unsigned short* Qh   = (unsigned short*)(ws + 24 * MB);  // 8 MB
    unsigned short* Kh   = (unsigned short*)(ws + 32 * MB);  // 8 MB
    unsigned short* Vt   = (unsigned short*)(ws + 40 * MB);  // 8 MB (direct from gemm)
    unsigned short* Wt   = (unsigned short*)(ws + 48 * MB);  // 8 MB (4 x 2MB)
    unsigned short* out_h = qb;   // reuse: qb dead after gemm_qkv

    float* out_f = (float*)d_out;                 // (B,S,D) fp32
    float* attn  = out_f + (size_t)BB * SS * DD;  // (B,H,S,S) fp32

    conv_bf16<<<dim3(2048, 1, 3), 256, 0, stream>>>(q, k, v, qb, kb, vb);
    trans_w<<<dim3(16, 16, 4), 256, 0, stream>>>(Wq, Wk, Wv, Wo, Wt);
    gemm_qkv<<<dim3(8, 32, 3), 256, 0, stream>>>(qb, kb, vb, Wt, bq, bk, bv,
                                                 Qh, Kh, Vt);
    attn_kernel<<<dim3(32, 32), 256, 0, stream>>>(Qh, Kh, Vt, mask, attn, out_h);
    gemm_o<<<dim3(16, 32), 256, 0, stream>>>(out_h, Wt, bo, out_f);
}

// Round 5
// 785.426 us; speedup vs baseline: 1.0600x; 1.0016x over previous
//
#include <hip/hip_runtime.h>
#include <hip/hip_bf16.h>

#define BB 2
#define SS 2048
#define DD 1024
#define HH 16
#define DEP 64

typedef short bf16x8 __attribute__((ext_vector_type(8)));
typedef float f32x4 __attribute__((ext_vector_type(4)));
typedef unsigned short us8 __attribute__((ext_vector_type(8)));
typedef unsigned short us4 __attribute__((ext_vector_type(4)));

static __device__ __forceinline__ unsigned short f2bf(float f) {
    unsigned int u = __float_as_uint(f);
    u += 0x7FFFu + ((u >> 16) & 1u);   // RNE
    return (unsigned short)(u >> 16);
}

// async global->LDS, 16B per lane. LDS base is wave-uniform; HW writes
// base + lane*16.
__device__ __forceinline__ void gl_lds16(const void* g, void* l) {
    __builtin_amdgcn_global_load_lds(
        (const __attribute__((address_space(1))) unsigned int*)g,
        (__attribute__((address_space(3))) unsigned int*)l, 16, 0, 0);
}

// wave-private LDS fence: only LDS ops drain (lgkmcnt), NOT vmcnt — global
// loads/stores stay in flight across it.
__device__ __forceinline__ void lds_fence() {
    asm volatile("s_waitcnt lgkmcnt(0)" ::: "memory");
}

// ---------------------------------------------------------------------------
// prep: fused conv_bf16 (z=0..2) + trans_w (z=3). The two jobs are
// independent and each tiny; one launch lets them fill the machine together
// and removes a serial launch+drain gap.
//   z<3 : fp32->bf16 convert of q/k/v, blockIdx.x 0..2047
//   z==3: weight transpose+convert, blockIdx.x 0..1023 encodes (wsel,ky,nx)
// ---------------------------------------------------------------------------
__global__ __launch_bounds__(256) void prep(
    const float* __restrict__ q, const float* __restrict__ k,
    const float* __restrict__ v, unsigned short* __restrict__ qb,
    unsigned short* __restrict__ kb, unsigned short* __restrict__ vb,
    const float* __restrict__ Wq, const float* __restrict__ Wk,
    const float* __restrict__ Wv, const float* __restrict__ Wo,
    unsigned short* __restrict__ Wt)
{
    const int z = blockIdx.z;
    const int t = threadIdx.x;
    if (z < 3) {
        const float* src = (z == 0) ? q : (z == 1) ? k : v;
        unsigned short* dst = (z == 0) ? qb : (z == 1) ? kb : vb;
        size_t i = ((size_t)blockIdx.x * 256 + t) * 8;
        float4 a = *(const float4*)(src + i);
        float4 b = *(const float4*)(src + i + 4);
        us8 o;
        o[0] = f2bf(a.x); o[1] = f2bf(a.y); o[2] = f2bf(a.z); o[3] = f2bf(a.w);
        o[4] = f2bf(b.x); o[5] = f2bf(b.y); o[6] = f2bf(b.z); o[7] = f2bf(b.w);
        *(us8*)(dst + i) = o;
        return;
    }
    // ---- trans_w path ----
    if (blockIdx.x >= 1024) return;
    __shared__ unsigned short T[64][72];
    const int wsel = blockIdx.x >> 8;           // 0..3
    const int k0 = ((blockIdx.x >> 4) & 15) * 64;
    const int n0 = (blockIdx.x & 15) * 64;
    const float* W = (wsel == 0) ? Wq : (wsel == 1) ? Wk : (wsel == 2) ? Wv : Wo;
    unsigned short* D = Wt + (size_t)wsel * 1024 * 1024;
    #pragma unroll
    for (int it = 0; it < 4; ++it) {
        int id = t + it * 256;       // 0..1023
        int kk = id >> 4;            // 64 rows
        int nn = (id & 15) * 4;
        float4 x = *(const float4*)(W + (size_t)(k0 + kk) * 1024 + n0 + nn);
        T[kk][nn + 0] = f2bf(x.x); T[kk][nn + 1] = f2bf(x.y);
        T[kk][nn + 2] = f2bf(x.z); T[kk][nn + 3] = f2bf(x.w);
    }
    __syncthreads();
    #pragma unroll
    for (int it = 0; it < 2; ++it) {
        int id = t + it * 256;       // 0..511
        int nn = id >> 3;            // 64
        int c8 = (id & 7) * 8;
        us8 o;
        #pragma unroll
        for (int j = 0; j < 8; ++j) o[j] = T[c8 + j][nn];
        *(us8*)(D + (size_t)(n0 + nn) * 1024 + k0 + c8) = o;
    }
}

// ---------------------------------------------------------------------------
// bf16 GEMM: A (4096 x 1024 bf16), Bt (1024 x 1024 bf16, N-major),
// 128x128 tile, BK=32, double-buffered global_load_lds + counted vmcnt.
// MODE 0: store bf16 head-split (b,h,s,dd).
// MODE 2: store bf16 TRANSPOSED head-split Vt[(b,h,dd)][s].
// ---------------------------------------------------------------------------
template <int MODE>
__device__ __forceinline__ void gemm_bt_body(
    const unsigned short* __restrict__ A, const unsigned short* __restrict__ Bt,
    const float* __restrict__ bias, unsigned short* __restrict__ OutB)
{
    __shared__ unsigned short As[2][128 * 32];
    __shared__ unsigned short Bs[2][128 * 32];
    const int t = threadIdx.x;
    const int m0 = blockIdx.y * 128, n0 = blockIdx.x * 128;
    const int w = t >> 6, lane = t & 63, g = lane >> 4, li = lane & 15;
    const int wr = (w & 1) * 64, wc = (w >> 1) * 64;
    const int lrow = lane >> 2, lcol = (lane & 3) * 8;
    const int c0 = w * 2, c1 = w * 2 + 1;          // 16-row chunks (wave-uniform)
    const int row0 = c0 * 16 + lrow, row1 = c1 * 16 + lrow;

    f32x4 acc[4][4] = {};

    auto stage = [&](int buf, int k0) {
        gl_lds16(A  + (size_t)(m0 + row0) * 1024 + k0 + lcol, &As[buf][c0 * 512]);
        gl_lds16(A  + (size_t)(m0 + row1) * 1024 + k0 + lcol, &As[buf][c1 * 512]);
        gl_lds16(Bt + (size_t)(n0 + row0) * 1024 + k0 + lcol, &Bs[buf][c0 * 512]);
        gl_lds16(Bt + (size_t)(n0 + row1) * 1024 + k0 + lcol, &Bs[buf][c1 * 512]);
    };
    auto compute = [&](int buf) {
        bf16x8 af[4], bfr[4];
        #pragma unroll
        for (int i = 0; i < 4; ++i)
            af[i] = *(const bf16x8*)&As[buf][(wr + i * 16 + li) * 32 + g * 8];
        #pragma unroll
        for (int j = 0; j < 4; ++j)
            bfr[j] = *(const bf16x8*)&Bs[buf][(wc + j * 16 + li) * 32 + g * 8];
        #pragma unroll
        for (int i = 0; i < 4; ++i)
            #pragma unroll
            for (int j = 0; j < 4; ++j)
                acc[i][j] = __builtin_amdgcn_mfma_f32_16x16x32_bf16(
                    af[i], bfr[j], acc[i][j], 0, 0, 0);
    };

    stage(0, 0);                                   // prologue: tile 0
    for (int k0 = 0; k0 < 1024 - 32; k0 += 32) {
        const int cur = (k0 >> 5) & 1;
        stage(cur ^ 1, k0 + 32);                   // issue next tile (in flight)
        asm volatile("s_waitcnt vmcnt(4)" ::: "memory");  // current arrived
        __builtin_amdgcn_s_barrier();
        compute(cur);
        __builtin_amdgcn_s_barrier();              // all reads of buf[cur] done
    }
    asm volatile("s_waitcnt vmcnt(0)" ::: "memory");
    __builtin_amdgcn_s_barrier();
    compute(1);                                    // last tile index 31 -> buf 1

    #pragma unroll
    for (int i = 0; i < 4; ++i) {
        #pragma unroll
        for (int j = 0; j < 4; ++j) {
            int n = n0 + wc + j * 16 + li;
            float bv = bias[n];
            if (MODE == 0) {
                #pragma unroll
                for (int r = 0; r < 4; ++r) {
                    int m = m0 + wr + i * 16 + g * 4 + r;
                    float val = acc[i][j][r] + bv;
                    int b = m >> 11, s = m & 2047, h = n >> 6, dd = n & 63;
                    OutB[(((size_t)(b * HH + h)) * SS + s) * DEP + dd] = f2bf(val);
                }
            } else {
                // MODE 2: transposed store, 4 consecutive s per thread
                int mb = m0 + wr + i * 16 + g * 4;   // multiple of 4
                int b = mb >> 11, s = mb & 2047;
                int h = n >> 6, dd = n & 63;
                us4 o4;
                #pragma unroll
                for (int r = 0; r < 4; ++r) o4[r] = f2bf(acc[i][j][r] + bv);
                *(us4*)(OutB + ((size_t)((b * HH + h) * DEP + dd)) * SS + s) = o4;
            }
        }
    }
}

__global__ __launch_bounds__(256) void gemm_qkv(
    const unsigned short* __restrict__ qb, const unsigned short* __restrict__ kb,
    const unsigned short* __restrict__ vb, const unsigned short* __restrict__ Wt,
    const float* __restrict__ bq, const float* __restrict__ bk,
    const float* __restrict__ bv,
    unsigned short* __restrict__ Qh, unsigned short* __restrict__ Kh,
    unsigned short* __restrict__ Vt)
{
    const int z = blockIdx.z;
    const unsigned short* A = (z == 0) ? qb : (z == 1) ? kb : vb;
    const unsigned short* B = Wt + (size_t)z * 1024 * 1024;
    const float* bi = (z == 0) ? bq : (z == 1) ? bk : bv;
    if (z == 2) {
        gemm_bt_body<2>(A, B, bi, Vt);     // V: direct transposed write
    } else {
        unsigned short* O = (z == 0) ? Qh : Kh;
        gemm_bt_body<0>(A, B, bi, O);
    }
}

// ---------------------------------------------------------------------------
// gemm_o: A (4096 x 1024 bf16) x Wo^T -> fp32 out. 128x64 tiles, 512 blocks
// (2 blocks/CU, 2 waves/SIMD).
// ---------------------------------------------------------------------------
__global__ __launch_bounds__(256) void gemm_o(
    const unsigned short* __restrict__ A, const unsigned short* __restrict__ Wt4,
    const float* __restrict__ bo, float* __restrict__ Out)
{
    const unsigned short* Bt = Wt4 + (size_t)3 * 1024 * 1024;
    __shared__ unsigned short As[2][128 * 32];
    __shared__ unsigned short Bs[2][64 * 32];
    const int t = threadIdx.x;
    const int m0 = blockIdx.y * 128, n0 = blockIdx.x * 64;
    const int w = t >> 6, lane = t & 63, g = lane >> 4, li = lane & 15;
    const int wr = w * 32;                          // each wave: 32 rows x 64 cols
    const int lrow = lane >> 2, lcol = (lane & 3) * 8;
    const int ca0 = w * 2, ca1 = w * 2 + 1;         // A chunks (8 total)
    const int rowa0 = ca0 * 16 + lrow, rowa1 = ca1 * 16 + lrow;
    const int rowb = w * 16 + lrow;                 // B chunk w (4 total)

    f32x4 acc[2][4] = {};

    auto stage = [&](int buf, int k0) {
        gl_lds16(A  + (size_t)(m0 + rowa0) * 1024 + k0 + lcol, &As[buf][ca0 * 512]);
        gl_lds16(A  + (size_t)(m0 + rowa1) * 1024 + k0 + lcol, &As[buf][ca1 * 512]);
        gl_lds16(Bt + (size_t)(n0 + rowb) * 1024 + k0 + lcol, &Bs[buf][w * 512]);
    };
    auto compute = [&](int buf) {
        bf16x8 af[2], bfr[4];
        #pragma unroll
        for (int i = 0; i < 2; ++i)
            af[i] = *(const bf16x8*)&As[buf][(wr + i * 16 + li) * 32 + g * 8];
        #pragma unroll
        for (int j = 0; j < 4; ++j)
            bfr[j] = *(const bf16x8*)&Bs[buf][(j * 16 + li) * 32 + g * 8];
        #pragma unroll
        for (int i = 0; i < 2; ++i)
            #pragma unroll
            for (int j = 0; j < 4; ++j)
                acc[i][j] = __builtin_amdgcn_mfma_f32_16x16x32_bf16(
                    af[i], bfr[j], acc[i][j], 0, 0, 0);
    };

    stage(0, 0);
    for (int k0 = 0; k0 < 1024 - 32; k0 += 32) {
        const int cur = (k0 >> 5) & 1;
        stage(cur ^ 1, k0 + 32);
        asm volatile("s_waitcnt vmcnt(3)" ::: "memory");
        __builtin_amdgcn_s_barrier();
        compute(cur);
        __builtin_amdgcn_s_barrier();
    }
    asm volatile("s_waitcnt vmcnt(0)" ::: "memory");
    __builtin_amdgcn_s_barrier();
    compute(1);

    #pragma unroll
    for (int i = 0; i < 2; ++i) {
        #pragma unroll
        for (int j = 0; j < 4; ++j) {
            int n = n0 + j * 16 + li;
            float bv = bo[n];
            #pragma unroll
            for (int r = 0; r < 4; ++r) {
                int m = m0 + wr + i * 16 + g * 4 + r;
                Out[(size_t)m * 1024 + n] = acc[i][j][r] + bv;
            }
        }
    }
}

// ---------------------------------------------------------------------------
// Causal attention, two-pass softmax. One block = (bh, two 32-row strips for
// causal load balance). 4 waves, each wave owns 16 q-rows, no cross-wave
// barriers. __launch_bounds__(256,4): cap at 128 VGPR so 4 blocks/CU fit ->
// all 1024 blocks resident in one round (no 25% dispatch tail). The R3 kn[]
// K-prefetch was dropped to make that budget (its measured benefit was ~0);
// K loads sit at iteration top with ~PV-MFMA distance to first use.
// ---------------------------------------------------------------------------
__global__ __launch_bounds__(256, 4) void attn_kernel(
    const unsigned short* __restrict__ Qh, const unsigned short* __restrict__ Kh,
    const unsigned short* __restrict__ Vt, const float* __restrict__ mask,
    float* __restrict__ attn, unsigned short* __restrict__ out_h)
{
    __shared__ float Pf[4][2][16 * 36];   // per-wave double-buffered 16x32 tile
    const int bh = blockIdx.y;
    const int b = bh >> 4, h = bh & 15;
    const int t = threadIdx.x;
    const int w = t >> 6, lane = t & 63, g = lane >> 4, li = lane & 15;
    const int x = blockIdx.x;          // 0..31
    const int r0 = (w < 2) ? (x * 32 + w * 16) : (SS - 32 - x * 32 + (w - 2) * 16);
    const float scale = 0.125f;        // 1/sqrt(64)

    const unsigned short* Qb = Qh + (size_t)bh * SS * DEP;
    const unsigned short* Kb = Kh + (size_t)bh * SS * DEP;
    const unsigned short* Vb = Vt + (size_t)bh * DEP * SS;
    float* attn_b = attn + (size_t)bh * SS * SS;
    const float* mask_b = mask + (size_t)b * SS;

    bf16x8 aQ0 = *(const bf16x8*)(Qb + (size_t)(r0 + li) * DEP + g * 8);
    bf16x8 aQ1 = *(const bf16x8*)(Qb + (size_t)(r0 + li) * DEP + 32 + g * 8);

    // per-LANE softmax partials (no shuffles in the hot loop)
    float mL[4], lL[4];
    #pragma unroll
    for (int r = 0; r < 4; ++r) { mL[r] = -1e30f; lL[r] = 0.0f; }

    // ---- pass 1: exact row max + sum, 64-col chunks ----
    const int nch = ((r0 + 15) >> 6) + 1;
    for (int ch = 0; ch < nch; ++ch) {
        int cb = ch * 64;
        f32x4 c[4];
        #pragma unroll
        for (int tt = 0; tt < 4; ++tt) {
            const unsigned short* Kp = Kb + (size_t)(cb + tt * 16 + li) * DEP + g * 8;
            bf16x8 k0v = *(const bf16x8*)Kp;
            bf16x8 k1v = *(const bf16x8*)(Kp + 32);
            f32x4 z = {};
            z = __builtin_amdgcn_mfma_f32_16x16x32_bf16(aQ0, k0v, z, 0, 0, 0);
            z = __builtin_amdgcn_mfma_f32_16x16x32_bf16(aQ1, k1v, z, 0, 0, 0);
            c[tt] = z;
        }
        float mv[4];
        #pragma unroll
        for (int tt = 0; tt < 4; ++tt) mv[tt] = mask_b[cb + tt * 16 + li];
        #pragma unroll
        for (int r = 0; r < 4; ++r) {
            int row = r0 + g * 4 + r;
            float s[4];
            #pragma unroll
            for (int tt = 0; tt < 4; ++tt) {
                int col = cb + tt * 16 + li;
                float pen = fmaxf(mv[tt], (col > row) ? 1.0f : 0.0f);
                s[tt] = c[tt][r] * scale + pen * (-1e17f);
            }
            float cm = fmaxf(fmaxf(s[0], s[1]), fmaxf(s[2], s[3]));
            float mn = fmaxf(mL[r], cm);
            lL[r] = lL[r] * __expf(mL[r] - mn) +
                    __expf(s[0] - mn) + __expf(s[1] - mn) +
                    __expf(s[2] - mn) + __expf(s[3] - mn);
            mL[r] = mn;
        }
    }
    // ---- end-of-pass-1 merge across the 16 li lanes (once per wave) ----
    float m_[4], rl[4];
    #pragma unroll
    for (int r = 0; r < 4; ++r) {
        float m = mL[r], l = lL[r];
        #pragma unroll
        for (int d = 1; d < 16; d <<= 1) {
            float mo = __shfl_xor(m, d);
            float lo = __shfl_xor(l, d);
            float mn = fmaxf(m, mo);
            l = l * __expf(m - mn) + lo * __expf(mo - mn);
            m = mn;
        }
        m_[r] = m;
        rl[r] = 1.0f / l;
    }

    // ---- pass 2: recompute, write attn (full lines), accumulate P@V ----
    f32x4 o[4] = {};
    const int jjc = ((r0 + 15) >> 5) + 1;

    for (int jj = 0; jj < jjc; ++jj) {
        int cb = jj * 32;
        float* Pw = &Pf[w][jj & 1][0];
        // K + V fragments at iteration top: first use is ~QK-MFMA distance
        // away; prior iteration's PV + stores cover most of the latency.
        bf16x8 kc[4];
        {
            const unsigned short* Kp0 = Kb + (size_t)(cb + li) * DEP + g * 8;
            const unsigned short* Kp1 = Kb + (size_t)(cb + 16 + li) * DEP + g * 8;
            kc[0] = *(const bf16x8*)Kp0; kc[1] = *(const bf16x8*)(Kp0 + 32);
            kc[2] = *(const bf16x8*)Kp1; kc[3] = *(const bf16x8*)(Kp1 + 32);
        }
        bf16x8 vf[4];
        #pragma unroll
        for (int tt = 0; tt < 4; ++tt)
            vf[tt] = *(const bf16x8*)(Vb + (size_t)(tt * 16 + li) * SS + cb + g * 8);
        #pragma unroll
        for (int hh = 0; hh < 2; ++hh) {
            int ct = cb + hh * 16;
            f32x4 c = {};
            c = __builtin_amdgcn_mfma_f32_16x16x32_bf16(aQ0, kc[hh * 2 + 0], c, 0, 0, 0);
            c = __builtin_amdgcn_mfma_f32_16x16x32_bf16(aQ1, kc[hh * 2 + 1], c, 0, 0, 0);
            float mv = mask_b[ct + li];
            #pragma unroll
            for (int r = 0; r < 4; ++r) {
                int row = r0 + g * 4 + r;
                float pen = fmaxf(mv, (ct + li > row) ? 1.0f : 0.0f);
                float s = c[r] * scale + pen * (-1e17f);
                Pw[(g * 4 + r) * 36 + hh * 16 + li] = __expf(s - m_[r]) * rl[r];
            }
        }
        lds_fence();   // Pw writes visible within the wave
        #pragma unroll
        for (int it = 0; it < 2; ++it) {
            int rloc = it * 8 + (lane >> 3);
            int c4 = (lane & 7) * 4;
            f32x4 val = *(const f32x4*)&Pw[rloc * 36 + c4];
            __builtin_nontemporal_store(
                val, (f32x4*)(attn_b + (size_t)(r0 + rloc) * SS + cb + c4));
        }
        float pf[8];
        *(f32x4*)&pf[0] = *(const f32x4*)&Pw[li * 36 + g * 8];
        *(f32x4*)&pf[4] = *(const f32x4*)&Pw[li * 36 + g * 8 + 4];
        bf16x8 aP;
        #pragma unroll
        for (int i = 0; i < 8; ++i) aP[i] = (short)f2bf(pf[i]);
        #pragma unroll
        for (int tt = 0; tt < 4; ++tt)
            o[tt] = __builtin_amdgcn_mfma_f32_16x16x32_bf16(aP, vf[tt], o[tt], 0, 0, 0);
        // no trailing fence: next iter writes the OTHER Pw buffer
    }

    // ---- zero-fill fully-masked region ----
    for (int cb = jjc * 32; cb < SS; cb += 64) {
        int col = cb + li * 4;
        if (col < SS) {
            f32x4 z4 = {0.f, 0.f, 0.f, 0.f};
            #pragma unroll
            for (int r = 0; r < 4; ++r) {
                int row = r0 + g * 4 + r;
                __builtin_nontemporal_store(
                    z4, (f32x4*)(attn_b + (size_t)row * SS + col));
            }
        }
    }

    // ---- store out_h bf16 (b,s,D) via LDS, full lines ----
    unsigned short* Ow = (unsigned short*)&Pf[w][0][0];  // stride 72 shorts
    #pragma unroll
    for (int tt = 0; tt < 4; ++tt)
        #pragma unroll
        for (int r = 0; r < 4; ++r)
            Ow[(g * 4 + r) * 72 + tt * 16 + li] = f2bf(o[tt][r]);
    lds_fence();
    #pragma unroll
    for (int it = 0; it < 2; ++it) {
        int rloc = it * 8 + (lane >> 3);
        int c8 = (lane & 7) * 8;
        us8 val = *(const us8*)&Ow[rloc * 72 + c8];
        *(us8*)(out_h + ((size_t)b * SS + r0 + rloc) * DD + h * DEP + c8) = val;
    }
}

// ---------------------------------------------------------------------------
extern "C" void kernel_launch(void* const* d_in, const int* in_sizes, int n_in,
                              void* d_out, int out_size, void* d_ws, size_t ws_size,
                              hipStream_t stream) {
    const float* v    = (const float*)d_in[0];
    const float* k    = (const float*)d_in[1];
    const float* q    = (const float*)d_in[2];
    const float* mask = (const float*)d_in[3];
    const float* Wq   = (const float*)d_in[4];
    const float* bq   = (const float*)d_in[5];
    const float* Wk   = (const float*)d_in[6];
    const float* bk   = (const float*)d_in[7];
    const float* Wv   = (const float*)d_in[8];
    const float* bv   = (const float*)d_in[9];
    const float* Wo   = (const float*)d_in[10];
    const float* bo   = (const float*)d_in[11];

    char* ws = (char*)d_ws;
    const size_t MB = 1 << 20;
    unsigned short* qb   = (unsigned short*)(ws + 0 * MB);   // 8 MB (later out_h)
    unsigned short* kb   = (unsigned short*)(ws + 8 * MB);   // 8 MB
    unsigned short* vb   = (unsigned short*)(ws + 16 * MB);  // 8 MB
    unsigned short* Qh   = (unsigned short*)(ws + 24 * MB);  // 8 MB
    unsigned short* Kh   = (unsigned short*)(ws + 32 * MB);  // 8 MB
    unsigned short* Vt   = (unsigned short*)(ws + 40 * MB);  // 8 MB (direct from gemm)
    unsigned short* Wt   = (unsigned short*)(ws + 48 * MB);  // 8 MB (4 x 2MB)
    unsigned short* out_h = qb;   // reuse: qb dead after gemm_qkv

    float* out_f = (float*)d_out;                 // (B,S,D) fp32
    float* attn  = out_f + (size_t)BB * SS * DD;  // (B,H,S,S) fp32

    prep<<<dim3(2048, 1, 4), 256, 0, stream>>>(q, k, v, qb, kb, vb,
                                               Wq, Wk, Wv, Wo, Wt);
    gemm_qkv<<<dim3(8, 32, 3), 256, 0, stream>>>(qb, kb, vb, Wt, bq, bk, bv,
                                                 Qh, Kh, Vt);
    attn_kernel<<<dim3(32, 32), 256, 0, stream>>>(Qh, Kh, Vt, mask, attn, out_h);
    gemm_o<<<dim3(16, 32), 256, 0, stream>>>(out_h, Wt, bo, out_f);
}